// Round 1
// baseline (251.336 us; speedup 1.0000x reference)
//
#include <hip/hip_runtime.h>
#include <hip/hip_bf16.h>
#include <math.h>

#define L 2048
#define D 256
#define NEG_FLT_MAX (-3.402823466e38f)

typedef __attribute__((ext_vector_type(8))) short bf16x8;
typedef __attribute__((ext_vector_type(4))) float f32x4;
typedef __attribute__((ext_vector_type(4))) int i32x4;

__device__ __forceinline__ unsigned short f2bf(float f) {
    union { float f; unsigned int u; } v; v.f = f;
    unsigned int r = v.u + 0x7FFFu + ((v.u >> 16) & 1u);   // RNE
    return (unsigned short)(r >> 16);
}

// --- transpose Wv, Wo (f32 k-major) -> bf16 n-major ---------------------
__global__ __launch_bounds__(256) void wtrans_kernel(
    const float* __restrict__ Wv, const float* __restrict__ Wo,
    unsigned short* __restrict__ Wvt, unsigned short* __restrict__ Wot) {
    int idx = blockIdx.x * 256 + threadIdx.x;       // 0..131071
    int which = idx >> 16;
    int e = idx & 65535;
    int n = e >> 8, k = e & 255;
    const float* W = which ? Wo : Wv;
    unsigned short* Wt = which ? Wot : Wvt;
    Wt[n * 256 + k] = f2bf(W[k * 256 + n]);
}

// --- LDS-free GEMM: C[8192,256] = A[8192,256] @ W + bias ----------------
// MODE 0: out bf16, stored TRANSPOSED into Vt[b][n][j]   (v projection)
// MODE 1: out f32 row-major into Cout                    (final output)
template<int MODE>
__global__ __launch_bounds__(256) void gemm_kernel(
    const float* __restrict__ A,
    const unsigned short* __restrict__ Wt,   // [256][256] bf16 n-major
    const float* __restrict__ bias,
    unsigned short* __restrict__ Vt,
    float* __restrict__ Cout) {
    const int wave = threadIdx.x >> 6;
    const int lane = threadIdx.x & 63;
    const int mh = wave >> 1, nh = wave & 1;
    const int lm = lane & 15, q = lane >> 4;
    const int m0 = blockIdx.x * 64;
    const int n0 = blockIdx.y * 128;

    f32x4 acc[2][4];
#pragma unroll
    for (int i = 0; i < 2; i++)
#pragma unroll
        for (int j = 0; j < 4; j++) acc[i][j] = (f32x4)(0.f);

    int arow[2];
    arow[0] = m0 + mh * 32 + lm;
    arow[1] = arow[0] + 16;
    int ncol[4];
#pragma unroll
    for (int nf = 0; nf < 4; nf++) ncol[nf] = n0 + nh * 64 + nf * 16 + lm;

    for (int k0 = 0; k0 < 256; k0 += 32) {
        int kq = k0 + q * 8;
        bf16x8 bfr[4];
#pragma unroll
        for (int nf = 0; nf < 4; nf++)
            bfr[nf] = *reinterpret_cast<const bf16x8*>(Wt + ncol[nf] * 256 + kq);
        bf16x8 afr[2];
#pragma unroll
        for (int mf = 0; mf < 2; mf++) {
            const float* ap = A + arow[mf] * 256 + kq;
            f32x4 a0 = *reinterpret_cast<const f32x4*>(ap);
            f32x4 a1 = *reinterpret_cast<const f32x4*>(ap + 4);
            bf16x8 t;
#pragma unroll
            for (int e = 0; e < 4; e++) t[e] = (short)f2bf(a0[e]);
#pragma unroll
            for (int e = 0; e < 4; e++) t[4 + e] = (short)f2bf(a1[e]);
            afr[mf] = t;
        }
#pragma unroll
        for (int mf = 0; mf < 2; mf++)
#pragma unroll
            for (int nf = 0; nf < 4; nf++)
                acc[mf][nf] = __builtin_amdgcn_mfma_f32_16x16x32_bf16(
                    afr[mf], bfr[nf], acc[mf][nf], 0, 0, 0);
    }

#pragma unroll
    for (int mf = 0; mf < 2; mf++) {
        int mrow = m0 + mh * 32 + mf * 16 + q * 4;   // rows mrow..mrow+3
#pragma unroll
        for (int nf = 0; nf < 4; nf++) {
            int n = ncol[nf];
            float bias_n = bias[n];
            if (MODE == 0) {
                int b = mrow >> 11;
                int j = mrow & 2047;
                unsigned short* dst = Vt + (size_t)b * (D * L) + (size_t)n * L + j;
                ushort4 pk;
                pk.x = f2bf(acc[mf][nf][0] + bias_n);
                pk.y = f2bf(acc[mf][nf][1] + bias_n);
                pk.z = f2bf(acc[mf][nf][2] + bias_n);
                pk.w = f2bf(acc[mf][nf][3] + bias_n);
                *reinterpret_cast<ushort4*>(dst) = pk;
            } else {
#pragma unroll
                for (int r = 0; r < 4; r++)
                    Cout[(size_t)(mrow + r) * 256 + n] = acc[mf][nf][r] + bias_n;
            }
        }
    }
}

// --- fused mask + online-softmax + P@V (flash style, j-split x2) --------
// grid 512: blk -> rb = blk>>1 (row block of 32), js = blk&1 (j half)
// partial layout per block: acc[32][256] f32, then m[32], l[32]
__global__ __launch_bounds__(256) void attn_kernel(
    const float* __restrict__ atten, const float* __restrict__ mask,
    const int* __restrict__ pad, const unsigned short* __restrict__ Vt,
    float* __restrict__ part) {
    const int blk = blockIdx.x;
    const int rb = blk >> 1, js = blk & 1;
    const int b = rb >> 6;
    const int i0 = (rb & 63) * 32;
    const int tid = threadIdx.x;
    const int wave = tid >> 6, lane = tid & 63;
    const int lm = lane & 15, q = lane >> 4;
    const int r = tid >> 3;            // softmax row 0..31
    const int c0 = (tid & 7) * 8;      // j offset within 64-tile

    __shared__ __align__(16) unsigned short Plds[2][32][72];
    __shared__ float alpha_lds[2][32];

    f32x4 acc[2][4];
#pragma unroll
    for (int i = 0; i < 2; i++)
#pragma unroll
        for (int j = 0; j < 4; j++) acc[i][j] = (f32x4)(0.f);

    float m_run = -INFINITY, l_run = 0.f;

    const size_t rowoff = ((size_t)(b * L + i0 + r)) * L + js * 1024 + c0;
    const float* at_row = atten + rowoff;
    const float* mk_row = mask + rowoff;
    const int* pd_row = pad + rowoff;
    const unsigned short* vt_b = Vt + (size_t)b * (D * L) + js * 1024;

    for (int jt = 0; jt < 16; jt++) {
        const int j0 = jt * 64;
        // B fragments straight from global Vt (L2-resident)
        bf16x8 bfr[2][4];
#pragma unroll
        for (int kk = 0; kk < 2; kk++)
#pragma unroll
            for (int nf = 0; nf < 4; nf++) {
                int n = wave * 64 + nf * 16 + lm;
                bfr[kk][nf] = *reinterpret_cast<const bf16x8*>(
                    vt_b + (size_t)n * L + j0 + kk * 32 + q * 8);
            }
        // masked logits for this thread's 8 j's
        f32x4 a0 = *reinterpret_cast<const f32x4*>(at_row + j0);
        f32x4 a1 = *reinterpret_cast<const f32x4*>(at_row + j0 + 4);
        f32x4 k0 = *reinterpret_cast<const f32x4*>(mk_row + j0);
        f32x4 k1 = *reinterpret_cast<const f32x4*>(mk_row + j0 + 4);
        i32x4 p0 = *reinterpret_cast<const i32x4*>(pd_row + j0);
        i32x4 p1 = *reinterpret_cast<const i32x4*>(pd_row + j0 + 4);
        float s[8];
#pragma unroll
        for (int e = 0; e < 4; e++) {
            float sv = (k0[e] < 0.5f) ? NEG_FLT_MAX : a0[e];
            s[e] = (p0[e] == 0) ? -INFINITY : sv;
            float sw = (k1[e] < 0.5f) ? NEG_FLT_MAX : a1[e];
            s[4 + e] = (p1[e] == 0) ? -INFINITY : sw;
        }
        float tmax = s[0];
#pragma unroll
        for (int e = 1; e < 8; e++) tmax = fmaxf(tmax, s[e]);
#pragma unroll
        for (int off = 1; off < 8; off <<= 1) tmax = fmaxf(tmax, __shfl_xor(tmax, off));
        float m_new = fmaxf(m_run, tmax);
        bool inf_row = (m_new == -INFINITY);
        float alpha = inf_row ? 1.f : __expf(m_run - m_new);
        float psum = 0.f;
        bf16x8 pk;
#pragma unroll
        for (int e = 0; e < 8; e++) {
            float pv = inf_row ? 0.f : __expf(s[e] - m_new);
            psum += pv;
            pk[e] = (short)f2bf(pv);
        }
#pragma unroll
        for (int off = 1; off < 8; off <<= 1) psum += __shfl_xor(psum, off);
        l_run = l_run * alpha + psum;
        m_run = m_new;

        const int par = jt & 1;
        *reinterpret_cast<bf16x8*>(&Plds[par][r][c0]) = pk;
        if ((tid & 7) == 0) alpha_lds[par][r] = alpha;
        __syncthreads();

        // rescale accumulator rows by alpha
        float al[2][4];
#pragma unroll
        for (int mf = 0; mf < 2; mf++)
#pragma unroll
            for (int rg = 0; rg < 4; rg++) al[mf][rg] = alpha_lds[par][mf * 16 + q * 4 + rg];
#pragma unroll
        for (int mf = 0; mf < 2; mf++)
#pragma unroll
            for (int nf = 0; nf < 4; nf++)
#pragma unroll
                for (int rg = 0; rg < 4; rg++) acc[mf][nf][rg] *= al[mf][rg];

        // P @ V
#pragma unroll
        for (int kk = 0; kk < 2; kk++)
#pragma unroll
            for (int mf = 0; mf < 2; mf++) {
                bf16x8 afr = *reinterpret_cast<const bf16x8*>(
                    &Plds[par][mf * 16 + lm][kk * 32 + q * 8]);
#pragma unroll
                for (int nf = 0; nf < 4; nf++)
                    acc[mf][nf] = __builtin_amdgcn_mfma_f32_16x16x32_bf16(
                        afr, bfr[kk][nf], acc[mf][nf], 0, 0, 0);
            }
    }

    // store partial (acc f32, m, l)
    float* pbase = part + (size_t)blk * 8256;
#pragma unroll
    for (int mf = 0; mf < 2; mf++)
#pragma unroll
        for (int nf = 0; nf < 4; nf++) {
            int n = wave * 64 + nf * 16 + lm;
#pragma unroll
            for (int rg = 0; rg < 4; rg++)
                pbase[(mf * 16 + q * 4 + rg) * 256 + n] = acc[mf][nf][rg];
        }
    if ((tid & 7) == 0) {
        pbase[8192 + r] = m_run;
        pbase[8224 + r] = l_run;
    }
}

// --- combine the 2 j-partials, divide by l, write out1 f32 --------------
__global__ __launch_bounds__(256) void combine_kernel(
    const float* __restrict__ part, float* __restrict__ out1) {
    const int rb = blockIdx.x;        // 0..255
    const int t = threadIdx.x;
    const int r = t >> 3;             // 0..31
    const int n0 = (t & 7) * 32;
    const float* p0 = part + (size_t)(rb * 2) * 8256;
    const float* p1 = p0 + 8256;
    float m0 = p0[8192 + r], l0 = p0[8224 + r];
    float m1 = p1[8192 + r], l1 = p1[8224 + r];
    float M = fmaxf(m0, m1);
    float w0 = (m0 == -INFINITY) ? 0.f : __expf(m0 - M);
    float w1 = (m1 == -INFINITY) ? 0.f : __expf(m1 - M);
    float inv = 1.f / (l0 * w0 + l1 * w1);
    w0 *= inv; w1 *= inv;
    float* dst = out1 + ((size_t)rb * 32 + r) * 256 + n0;
    const float* a0 = p0 + r * 256 + n0;
    const float* a1 = p1 + r * 256 + n0;
#pragma unroll
    for (int e = 0; e < 32; e += 4) {
        f32x4 x0 = *reinterpret_cast<const f32x4*>(a0 + e);
        f32x4 x1 = *reinterpret_cast<const f32x4*>(a1 + e);
        f32x4 o = x0 * w0 + x1 * w1;
        *reinterpret_cast<f32x4*>(dst + e) = o;
    }
}

extern "C" void kernel_launch(void* const* d_in, const int* in_sizes, int n_in,
                              void* d_out, int out_size, void* d_ws, size_t ws_size,
                              hipStream_t stream) {
    (void)in_sizes; (void)n_in; (void)out_size; (void)ws_size;
    const float* atten = (const float*)d_in[0];
    const float* value = (const float*)d_in[1];
    const float* mask  = (const float*)d_in[2];
    const int*   pad   = (const int*)d_in[3];
    const float* Wv    = (const float*)d_in[4];
    const float* bv    = (const float*)d_in[5];
    const float* Wo    = (const float*)d_in[6];
    const float* bo    = (const float*)d_in[7];
    float* out = (float*)d_out;

    char* ws = (char*)d_ws;
    unsigned short* Vt  = (unsigned short*)(ws);              // 4 MB  bf16 [B][D][L]
    unsigned short* Wvt = (unsigned short*)(ws + 4194304);    // 128 KB
    unsigned short* Wot = (unsigned short*)(ws + 4325376);    // 128 KB
    float* out1 = (float*)(ws + 4456448);                     // 8 MB  f32 [8192][256]
    float* part = (float*)(ws + 12845056);                    // 512 * 33024 B

    wtrans_kernel<<<512, 256, 0, stream>>>(Wv, Wo, Wvt, Wot);
    gemm_kernel<0><<<dim3(128, 2), 256, 0, stream>>>(value, Wvt, bv, Vt, nullptr);
    attn_kernel<<<512, 256, 0, stream>>>(atten, mask, pad, Vt, part);
    combine_kernel<<<256, 256, 0, stream>>>(part, out1);
    gemm_kernel<1><<<dim3(128, 2), 256, 0, stream>>>(out1, Wot, bo, nullptr, out);
}